// Round 6
// baseline (210.559 us; speedup 1.0000x reference)
//
#include <hip/hip_runtime.h>

#define LRELU(x) ((x) > 0.f ? (x) : 0.2f*(x))
typedef unsigned int uint;

__device__ inline unsigned short f2bf(float f) {
    union { float f; unsigned u; } v; v.f = f;
    unsigned r = v.u + 0x7FFF + ((v.u >> 16) & 1);
    return (unsigned short)(r >> 16);
}
__device__ inline uint packbf(float a, float b) {
    return (uint)f2bf(a) | ((uint)f2bf(b) << 16);
}
__device__ inline float bflo(uint u){ union{uint u; float f;}v; v.u = u<<16; return v.f; }
__device__ inline float bfhi(uint u){ union{uint u; float f;}v; v.u = u & 0xFFFF0000u; return v.f; }
__device__ inline float f4get(const float4& v, int i) {
    return i==0 ? v.x : i==1 ? v.y : i==2 ? v.z : v.w;
}

// ---------------- CSR build: atomic-free two-level bucket sort ----------------
// ebuf entries packed: (src << 7) | (dst & 127)

#define CSR_SHIFT 7
#define CSR_NBLK  512

__global__ __launch_bounds__(256) void bucket_count_kernel(
    const int* __restrict__ dst, int E, int chunk, int nb,
    int* __restrict__ blockCntT)
{
    __shared__ int cnt[1024];
    int t = threadIdx.x, k = blockIdx.x;
    for (int i = t; i < nb; i += 256) cnt[i] = 0;
    __syncthreads();
    int e0 = k * chunk, e1 = min(e0 + chunk, E);
    for (int e = e0 + t; e < e1; e += 256)
        atomicAdd(&cnt[dst[e] >> CSR_SHIFT], 1);
    __syncthreads();
    for (int b = t; b < nb; b += 256)
        blockCntT[b * CSR_NBLK + k] = cnt[b];
}

__global__ __launch_bounds__(512) void row_scan_kernel(
    int* __restrict__ blockCntT, int* __restrict__ tot)
{
    __shared__ int sm[512];
    int b = blockIdx.x, t = threadIdx.x;
    int* row = blockCntT + b * CSR_NBLK;
    int v = row[t];
    sm[t] = v;
    __syncthreads();
    for (int off = 1; off < 512; off <<= 1) {
        int u = (t >= off) ? sm[t - off] : 0;
        __syncthreads(); sm[t] += u; __syncthreads();
    }
    row[t] = sm[t] - v;            // exclusive within bucket
    if (t == 511) tot[b] = sm[511];
}

__global__ __launch_bounds__(1024) void total_scan_kernel(
    const int* __restrict__ tot, int nb, int* __restrict__ bucketBase)
{
    __shared__ int sm[1024];
    int t = threadIdx.x;
    int v = (t < nb) ? tot[t] : 0;
    sm[t] = v;
    __syncthreads();
    for (int off = 1; off < 1024; off <<= 1) {
        int u = (t >= off) ? sm[t - off] : 0;
        __syncthreads(); sm[t] += u; __syncthreads();
    }
    if (t < nb) bucketBase[t] = sm[t] - v;
    if (t == 1023) bucketBase[nb] = sm[1023];
}

__global__ __launch_bounds__(256) void bucket_scatter_kernel(
    const int* __restrict__ src, const int* __restrict__ dst, int E, int chunk, int nb,
    const int* __restrict__ blockCntT, const int* __restrict__ bucketBase,
    uint* __restrict__ ebuf)
{
    __shared__ int cur[1024];
    int t = threadIdx.x, k = blockIdx.x;
    for (int b = t; b < nb; b += 256)
        cur[b] = bucketBase[b] + blockCntT[b * CSR_NBLK + k];
    __syncthreads();
    int e0 = k * chunk, e1 = min(e0 + chunk, E);
    for (int e = e0 + t; e < e1; e += 256) {
        int d = dst[e], s_ = src[e];
        int pos = atomicAdd(&cur[d >> CSR_SHIFT], 1);
        ebuf[pos] = ((uint)s_ << 7) | (uint)(d & 127);
    }
}

__global__ __launch_bounds__(256) void local_csr_kernel(
    const uint* __restrict__ ebuf, const int* __restrict__ bucketBase,
    int n, int E, int* __restrict__ rowptr, int* __restrict__ csr)
{
    __shared__ int lbase[1 << CSR_SHIFT];
    __shared__ int lcur[1 << CSR_SHIFT];
    __shared__ int ldeg[1 << CSR_SHIFT];
    int b = blockIdx.x, t = threadIdx.x;
    int n0 = b << CSR_SHIFT;
    int base = bucketBase[b], end = bucketBase[b + 1];
    if (t < (1 << CSR_SHIFT)) ldeg[t] = 0;
    __syncthreads();
    for (int e = base + t; e < end; e += 256)
        atomicAdd(&ldeg[ebuf[e] & 127], 1);
    __syncthreads();
    if (t == 0) {
        int run = base;
        for (int i = 0; i < (1 << CSR_SHIFT); ++i) {
            lbase[i] = run; lcur[i] = run; run += ldeg[i];
        }
    }
    __syncthreads();
    int node = n0 + t;
    if (t < (1 << CSR_SHIFT) && node < n) rowptr[node] = lbase[t];
    if (b == 0 && t == 0) rowptr[n] = E;
    for (int e = base + t; e < end; e += 256) {
        uint ed = ebuf[e];
        int pos = atomicAdd(&lcur[ed & 127], 1);
        csr[pos] = (int)(ed >> 7);
    }
}

// ---------------- GEMM + fused alpha dots ----------------
// NPT=4 nodes per thread. COLS=128 -> fp8 e4m3 output; COLS=32 -> bf16 output.

template<int COLS, int HEADS>
__global__ __launch_bounds__(256) void gemm_alpha_kernel(
    const float* __restrict__ x, const float* __restrict__ W,
    const float* __restrict__ a_src, const float* __restrict__ a_dst,
    uint* __restrict__ hq, float* __restrict__ as_out,
    float* __restrict__ ad_out, int n)
{
    constexpr int K = 128;
    constexpr int CPT = COLS / 8;
    constexpr int NPT = 4;
    constexpr int DIM = COLS / HEADS;
    constexpr int TPH = DIM / CPT;
    constexpr int NSLOT = COLS / 4;
    __shared__ float4 WL[K * NSLOT];

    int t = threadIdx.x;
    for (int idx = t * 4; idx < K * COLS; idx += 1024) {
        float4 w = *(const float4*)(W + idx);
        int k = idx / COLS, c = idx % COLS;
        int slot = c >> 2;
        if (COLS == 128) slot = (slot >> 2) | ((slot & 3) << 3);
        WL[k * NSLOT + slot] = w;
    }
    __syncthreads();

    int m_ = t & 7;
    int node0 = blockIdx.x * (32 * NPT) + (t >> 3) * NPT;
    if (node0 >= n) return;
    int c0 = m_ * CPT;

    const float* xr[NPT];
#pragma unroll
    for (int i = 0; i < NPT; i++) xr[i] = x + (size_t)min(node0 + i, n - 1) * K;

    float acc[NPT][CPT];
#pragma unroll
    for (int i = 0; i < NPT; i++)
#pragma unroll
        for (int q = 0; q < CPT; q++) acc[i][q] = 0.f;

    for (int k4 = 0; k4 < K; k4 += 4) {
        float4 xv[NPT];
#pragma unroll
        for (int i = 0; i < NPT; i++) xv[i] = *(const float4*)(xr[i] + k4);
#pragma unroll
        for (int kk = 0; kk < 4; kk++) {
#pragma unroll
            for (int j = 0; j < CPT / 4; j++) {
                int slot = (COLS == 128) ? (m_ | (j << 3)) : m_;
                float4 w = WL[(k4 + kk) * NSLOT + slot];
#pragma unroll
                for (int i = 0; i < NPT; i++) {
                    float xa = f4get(xv[i], kk);
                    acc[i][j*4+0] += xa * w.x;
                    acc[i][j*4+1] += xa * w.y;
                    acc[i][j*4+2] += xa * w.z;
                    acc[i][j*4+3] += xa * w.w;
                }
            }
        }
    }

    int head = c0 / DIM, lc = c0 - head * DIM;
    float asc[CPT], adc[CPT];
#pragma unroll
    for (int q = 0; q < CPT; q++) {
        asc[q] = a_src[head * DIM + lc + q];
        adc[q] = a_dst[head * DIM + lc + q];
    }

#pragma unroll
    for (int i = 0; i < NPT; i++) {
        int node = node0 + i;
        if (node >= n) break;
        if constexpr (COLS == 128) {
            uint wds[4];
#pragma unroll
            for (int j = 0; j < 4; j++) {
                int u = 0;
                u = __builtin_amdgcn_cvt_pk_fp8_f32(acc[i][j*4+0], acc[i][j*4+1], u, false);
                u = __builtin_amdgcn_cvt_pk_fp8_f32(acc[i][j*4+2], acc[i][j*4+3], u, true);
                wds[j] = (uint)u;
            }
            *(uint4*)(hq + (size_t)node * 32 + m_ * 4) = make_uint4(wds[0], wds[1], wds[2], wds[3]);
        } else {
            uint w0 = packbf(acc[i][0], acc[i][1]);
            uint w1 = packbf(acc[i][2], acc[i][3]);
            *(uint2*)(hq + (size_t)node * 16 + m_ * 2) = make_uint2(w0, w1);
        }
        float ps = 0.f, pd = 0.f;
#pragma unroll
        for (int q = 0; q < CPT; q++) {
            ps += acc[i][q] * asc[q];
            pd += acc[i][q] * adc[q];
        }
#pragma unroll
        for (int off = 1; off < TPH; off <<= 1) {
            ps += __shfl_xor(ps, off);
            pd += __shfl_xor(pd, off);
        }
        if ((m_ & (TPH - 1)) == 0) {
            as_out[node * HEADS + head] = ps;
            ad_out[node * HEADS + head] = pd;
        }
    }
}

// ---------------- Layer-1 aggregation (fp8 gather, wave-independent) ----------
// One 64-lane wave per node; LDS staging is wave-private, so no block barriers:
// wave64 lockstep + in-order DS pipe + wave_barrier (compiler fence) suffice.
// Wave: stage 64 edges (all lanes), then 2 edge-groups x 32 lanes consume;
// lane covers dims 4l..4l+3 (one u32 = one 128B fp8 row per 32-lane group).

__global__ __launch_bounds__(256) void agg1_kernel(
    const float4* __restrict__ as1, const float4* __restrict__ ad1,
    const uint* __restrict__ h1q, const int* __restrict__ rowptr,
    const int* __restrict__ csr, const float* __restrict__ b1,
    float* __restrict__ hout, int n)
{
    __shared__ int   sIdx[4][64];
    __shared__ float sEx[4][64][4];

    int t = threadIdx.x;
    int w = t >> 6, tw = t & 63;
    int grp = tw >> 5, l = tw & 31;
    int head = l >> 3;
    int node = blockIdx.x * 4 + w;
    if (node >= n) return;

    float4 adv = ad1[node];
    int rp = rowptr[node], re = rowptr[node + 1];

    float a0 = 0.f, a1 = 0.f, a2 = 0.f, a3 = 0.f, den = 0.f;

    for (int base = rp; base < re; base += 64) {
        int cnt = min(64, re - base);
        if (tw < cnt) {
            int s = csr[base + tw];
            sIdx[w][tw] = s;
            float4 av = as1[s];
            sEx[w][tw][0] = __expf(LRELU(av.x + adv.x));
            sEx[w][tw][1] = __expf(LRELU(av.y + adv.y));
            sEx[w][tw][2] = __expf(LRELU(av.z + adv.z));
            sEx[w][tw][3] = __expf(LRELU(av.w + adv.w));
        }
        __builtin_amdgcn_wave_barrier();
#pragma unroll 8
        for (int e = grp; e < cnt; e += 2) {
            int s = sIdx[w][e];
            float ex = sEx[w][e][head];
            den += ex;
            uint u = h1q[(size_t)s * 32 + l];
            auto p0 = __builtin_amdgcn_cvt_pk_f32_fp8(u, false);
            auto p1 = __builtin_amdgcn_cvt_pk_f32_fp8(u, true);
            a0 += ex * p0[0]; a1 += ex * p0[1];
            a2 += ex * p1[0]; a3 += ex * p1[1];
        }
        __builtin_amdgcn_wave_barrier();
    }
    a0 += __shfl_down(a0, 32); a1 += __shfl_down(a1, 32);
    a2 += __shfl_down(a2, 32); a3 += __shfl_down(a3, 32);
    den += __shfl_down(den, 32);
    if (grp == 0) {
        float4 asv = as1[node];
        float ash = (head & 2) ? ((head & 1) ? asv.w : asv.z) : ((head & 1) ? asv.y : asv.x);
        float adh = (head & 2) ? ((head & 1) ? adv.w : adv.z) : ((head & 1) ? adv.y : adv.x);
        float ex = __expf(LRELU(ash + adh));
        den += ex;
        uint u = h1q[(size_t)node * 32 + l];
        auto p0 = __builtin_amdgcn_cvt_pk_f32_fp8(u, false);
        auto p1 = __builtin_amdgcn_cvt_pk_f32_fp8(u, true);
        a0 += ex * p0[0]; a1 += ex * p0[1];
        a2 += ex * p1[0]; a3 += ex * p1[1];
        float inv = 1.f / (den + 1e-16f);
        float4 bv = ((const float4*)b1)[l];
        float4 o;
        o.x = fmaxf(a0 * inv + bv.x, 0.f);
        o.y = fmaxf(a1 * inv + bv.y, 0.f);
        o.z = fmaxf(a2 * inv + bv.z, 0.f);
        o.w = fmaxf(a3 * inv + bv.w, 0.f);
        ((float4*)hout)[(size_t)node * 32 + l] = o;
    }
}

// ---------------- Layer-2 aggregation (bf16x2 gather, wave-independent) --------
// One wave per node; 4 edge-groups x 16 lanes; lane covers dims 2l,2l+1.

__global__ __launch_bounds__(256) void agg2_kernel(
    const float2* __restrict__ as2, const float2* __restrict__ ad2,
    const uint* __restrict__ h2q, const int* __restrict__ rowptr,
    const int* __restrict__ csr, const float* __restrict__ b2,
    float* __restrict__ hf, int n)
{
    __shared__ int   sIdx[4][64];
    __shared__ float sEx[4][64][2];

    int t = threadIdx.x;
    int w = t >> 6, tw = t & 63;
    int grp = tw >> 4, l = tw & 15;
    int head = l >> 3;
    int node = blockIdx.x * 4 + w;
    if (node >= n) return;

    float2 adv = ad2[node];
    float adh = head ? adv.y : adv.x;
    int rp = rowptr[node], re = rowptr[node + 1];

    float a0 = 0.f, a1 = 0.f, den = 0.f;

    for (int base = rp; base < re; base += 64) {
        int cnt = min(64, re - base);
        if (tw < cnt) {
            int s = csr[base + tw];
            sIdx[w][tw] = s;
            float2 av = as2[s];
            sEx[w][tw][0] = __expf(LRELU(av.x + adv.x));
            sEx[w][tw][1] = __expf(LRELU(av.y + adv.y));
        }
        __builtin_amdgcn_wave_barrier();
#pragma unroll 8
        for (int e = grp; e < cnt; e += 4) {
            int s = sIdx[w][e];
            float ex = sEx[w][e][head];
            den += ex;
            uint u = h2q[(size_t)s * 16 + l];
            a0 += ex * bflo(u);
            a1 += ex * bfhi(u);
        }
        __builtin_amdgcn_wave_barrier();
    }
    a0 += __shfl_xor(a0, 16); a1 += __shfl_xor(a1, 16); den += __shfl_xor(den, 16);
    a0 += __shfl_xor(a0, 32); a1 += __shfl_xor(a1, 32); den += __shfl_xor(den, 32);
    if (grp == 0) {
        float2 asv = as2[node];
        float ash = head ? asv.y : asv.x;
        float ex = __expf(LRELU(ash + adh));
        den += ex;
        uint u = h2q[(size_t)node * 16 + l];
        a0 += ex * bflo(u);
        a1 += ex * bfhi(u);
        float inv = 1.f / (den + 1e-16f);
        float v0 = a0 * inv, v1 = a1 * inv;
        float o0 = 0.5f * (v0 + __shfl_down(v0, 8));
        float o1 = 0.5f * (v1 + __shfl_down(v1, 8));
        if (l < 8) {
            *(float2*)(hf + (size_t)node * 16 + 2 * l) =
                make_float2(o0 + b2[2 * l], o1 + b2[2 * l + 1]);
        }
    }
}

// ---------------- Pooling + FC ----------------

__global__ __launch_bounds__(256) void pool_kernel(
    const float* __restrict__ hf, const int* __restrict__ batch,
    float* __restrict__ sums, float* __restrict__ counts, int n)
{
    int t = threadIdx.x;
    int d = t & 15, j = t >> 4;
    int base = blockIdx.x * 256 + j * 16;
    float run = 0.f, cnt = 0.f;
    int cg = -1;
    for (int i = 0; i < 16; ++i) {
        int nn = base + i;
        if (nn >= n) break;
        int g = batch[nn];
        if (g != cg) {
            if (cg >= 0) { atomicAdd(&sums[cg * 16 + d], run); if (d == 0) atomicAdd(&counts[cg], cnt); }
            cg = g; run = 0.f; cnt = 0.f;
        }
        run += hf[(size_t)nn * 16 + d];
        cnt += 1.f;
    }
    if (cg >= 0) { atomicAdd(&sums[cg * 16 + d], run); if (d == 0) atomicAdd(&counts[cg], cnt); }
}

__global__ void final_kernel(const float* __restrict__ sums, const float* __restrict__ counts,
                             const float* __restrict__ fcW, const float* __restrict__ fcb,
                             float* __restrict__ out, int G)
{
    int g = blockIdx.x * 64 + threadIdx.x;
    if (g < G) {
        float c = fmaxf(counts[g], 1.f);
        float s = 0.f;
        for (int dd = 0; dd < 16; ++dd) s += (sums[g * 16 + dd] / c) * fcW[dd];
        out[g] = s + fcb[0];
    }
}

// ---------------- launch ----------------

extern "C" void kernel_launch(void* const* d_in, const int* in_sizes, int n_in,
                              void* d_out, int out_size, void* d_ws, size_t ws_size,
                              hipStream_t stream)
{
    const float* x      = (const float*)d_in[0];
    const int*   ei     = (const int*)d_in[1];
    const int*   batch  = (const int*)d_in[2];
    const float* W1     = (const float*)d_in[3];
    const float* a_src1 = (const float*)d_in[4];
    const float* a_dst1 = (const float*)d_in[5];
    const float* b1     = (const float*)d_in[6];
    const float* W2     = (const float*)d_in[7];
    const float* a_src2 = (const float*)d_in[8];
    const float* a_dst2 = (const float*)d_in[9];
    const float* b2     = (const float*)d_in[10];
    const float* fcW    = (const float*)d_in[11];
    const float* fcb    = (const float*)d_in[12];
    float* out = (float*)d_out;

    int n = in_sizes[0] / 128;
    int E = in_sizes[1] / 2;
    int G = out_size;
    const int* srcA = ei;
    const int* dstA = ei + E;

    int nb = (n + (1 << CSR_SHIFT) - 1) >> CSR_SHIFT;
    int chunk = (E + CSR_NBLK - 1) / CSR_NBLK;

    char* p = (char*)d_ws;
    auto alloc = [&](size_t bytes) { char* r = p; p += (bytes + 255) & ~(size_t)255; return r; };
    int*   blockCntT  = (int*)alloc((size_t)nb * CSR_NBLK * 4);
    int*   tot        = (int*)alloc((size_t)nb * 4);
    int*   bucketBase = (int*)alloc((size_t)(nb + 1) * 4);
    int*   rowptr     = (int*)alloc((size_t)(n + 1) * 4);
    int*   csr        = (int*)alloc((size_t)E * 4);
    uint*  h1q        = (uint*)alloc((size_t)n * 32 * 4);    // fp8 x4 per uint
    float* as1        = (float*)alloc((size_t)n * 16);
    float* ad1        = (float*)alloc((size_t)n * 16);
    float* hrelu      = (float*)alloc((size_t)n * 128 * 4);
    uint*  h2q        = (uint*)alloc((size_t)n * 16 * 4);    // bf16 x2 per uint
    float* as2        = (float*)alloc((size_t)n * 8);
    float* ad2        = (float*)alloc((size_t)n * 8);
    float* hf         = (float*)alloc((size_t)n * 16 * 4);
    float* sums       = (float*)alloc((size_t)G * 16 * 4 + (size_t)G * 4);
    float* counts     = sums + G * 16;

    // edge staging buffer aliases hrelu; consumed by local_csr before agg1 writes.
    uint* ebuf = (uint*)hrelu;

    hipMemsetAsync(sums, 0, (size_t)G * 16 * 4 + (size_t)G * 4, stream);

    bucket_count_kernel<<<CSR_NBLK, 256, 0, stream>>>(dstA, E, chunk, nb, blockCntT);
    row_scan_kernel<<<nb, 512, 0, stream>>>(blockCntT, tot);
    total_scan_kernel<<<1, 1024, 0, stream>>>(tot, nb, bucketBase);
    bucket_scatter_kernel<<<CSR_NBLK, 256, 0, stream>>>(srcA, dstA, E, chunk, nb,
                                                        blockCntT, bucketBase, ebuf);
    local_csr_kernel<<<nb, 256, 0, stream>>>(ebuf, bucketBase, n, E, rowptr, csr);

    int gb = (n + 127) / 128;
    gemm_alpha_kernel<128, 4><<<gb, 256, 0, stream>>>(x, W1, a_src1, a_dst1, h1q, as1, ad1, n);
    agg1_kernel<<<(n + 3) / 4, 256, 0, stream>>>((const float4*)as1, (const float4*)ad1,
                                                 h1q, rowptr, csr, b1, hrelu, n);
    gemm_alpha_kernel<32, 2><<<gb, 256, 0, stream>>>(hrelu, W2, a_src2, a_dst2, h2q, as2, ad2, n);
    agg2_kernel<<<(n + 3) / 4, 256, 0, stream>>>((const float2*)as2, (const float2*)ad2,
                                                 h2q, rowptr, csr, b2, hf, n);
    pool_kernel<<<(n + 255) / 256, 256, 0, stream>>>(hf, batch, sums, counts, n);
    final_kernel<<<1, 64, 0, stream>>>(sums, counts, fcW, fcb, out, G);
}

// Round 7
// 209.258 us; speedup vs baseline: 1.0062x; 1.0062x over previous
//
#include <hip/hip_runtime.h>

#define LRELU(x) ((x) > 0.f ? (x) : 0.2f*(x))
typedef unsigned int uint;

__device__ inline unsigned short f2bf(float f) {
    union { float f; unsigned u; } v; v.f = f;
    unsigned r = v.u + 0x7FFF + ((v.u >> 16) & 1);
    return (unsigned short)(r >> 16);
}
__device__ inline uint packbf(float a, float b) {
    return (uint)f2bf(a) | ((uint)f2bf(b) << 16);
}
__device__ inline float bflo(uint u){ union{uint u; float f;}v; v.u = u<<16; return v.f; }
__device__ inline float bfhi(uint u){ union{uint u; float f;}v; v.u = u & 0xFFFF0000u; return v.f; }
__device__ inline float f4get(const float4& v, int i) {
    return i==0 ? v.x : i==1 ? v.y : i==2 ? v.z : v.w;
}

// ---------------- CSR build: atomic-free two-level bucket sort ----------------
// ebuf entries packed: (src << 7) | (dst & 127)

#define CSR_SHIFT 7
#define CSR_NBLK  512

__global__ __launch_bounds__(256) void bucket_count_kernel(
    const int* __restrict__ dst, int E, int chunk, int nb,
    int* __restrict__ blockCntT)
{
    __shared__ int cnt[1024];
    int t = threadIdx.x, k = blockIdx.x;
    for (int i = t; i < nb; i += 256) cnt[i] = 0;
    __syncthreads();
    int e0 = k * chunk, e1 = min(e0 + chunk, E);
    for (int e = e0 + t; e < e1; e += 256)
        atomicAdd(&cnt[dst[e] >> CSR_SHIFT], 1);
    __syncthreads();
    for (int b = t; b < nb; b += 256)
        blockCntT[b * CSR_NBLK + k] = cnt[b];
}

__global__ __launch_bounds__(512) void row_scan_kernel(
    int* __restrict__ blockCntT, int* __restrict__ tot)
{
    __shared__ int sm[512];
    int b = blockIdx.x, t = threadIdx.x;
    int* row = blockCntT + b * CSR_NBLK;
    int v = row[t];
    sm[t] = v;
    __syncthreads();
    for (int off = 1; off < 512; off <<= 1) {
        int u = (t >= off) ? sm[t - off] : 0;
        __syncthreads(); sm[t] += u; __syncthreads();
    }
    row[t] = sm[t] - v;            // exclusive within bucket
    if (t == 511) tot[b] = sm[511];
}

__global__ __launch_bounds__(1024) void total_scan_kernel(
    const int* __restrict__ tot, int nb, int* __restrict__ bucketBase)
{
    __shared__ int sm[1024];
    int t = threadIdx.x;
    int v = (t < nb) ? tot[t] : 0;
    sm[t] = v;
    __syncthreads();
    for (int off = 1; off < 1024; off <<= 1) {
        int u = (t >= off) ? sm[t - off] : 0;
        __syncthreads(); sm[t] += u; __syncthreads();
    }
    if (t < nb) bucketBase[t] = sm[t] - v;
    if (t == 1023) bucketBase[nb] = sm[1023];
}

__global__ __launch_bounds__(256) void bucket_scatter_kernel(
    const int* __restrict__ src, const int* __restrict__ dst, int E, int chunk, int nb,
    const int* __restrict__ blockCntT, const int* __restrict__ bucketBase,
    uint* __restrict__ ebuf)
{
    __shared__ int cur[1024];
    int t = threadIdx.x, k = blockIdx.x;
    for (int b = t; b < nb; b += 256)
        cur[b] = bucketBase[b] + blockCntT[b * CSR_NBLK + k];
    __syncthreads();
    int e0 = k * chunk, e1 = min(e0 + chunk, E);
    for (int e = e0 + t; e < e1; e += 256) {
        int d = dst[e], s_ = src[e];
        int pos = atomicAdd(&cur[d >> CSR_SHIFT], 1);
        ebuf[pos] = ((uint)s_ << 7) | (uint)(d & 127);
    }
}

__global__ __launch_bounds__(256) void local_csr_kernel(
    const uint* __restrict__ ebuf, const int* __restrict__ bucketBase,
    int n, int E, int* __restrict__ rowptr, int* __restrict__ csr)
{
    __shared__ int lbase[1 << CSR_SHIFT];
    __shared__ int lcur[1 << CSR_SHIFT];
    __shared__ int ldeg[1 << CSR_SHIFT];
    int b = blockIdx.x, t = threadIdx.x;
    int n0 = b << CSR_SHIFT;
    int base = bucketBase[b], end = bucketBase[b + 1];
    if (t < (1 << CSR_SHIFT)) ldeg[t] = 0;
    __syncthreads();
    for (int e = base + t; e < end; e += 256)
        atomicAdd(&ldeg[ebuf[e] & 127], 1);
    __syncthreads();
    if (t == 0) {
        int run = base;
        for (int i = 0; i < (1 << CSR_SHIFT); ++i) {
            lbase[i] = run; lcur[i] = run; run += ldeg[i];
        }
    }
    __syncthreads();
    int node = n0 + t;
    if (t < (1 << CSR_SHIFT) && node < n) rowptr[node] = lbase[t];
    if (b == 0 && t == 0) rowptr[n] = E;
    for (int e = base + t; e < end; e += 256) {
        uint ed = ebuf[e];
        int pos = atomicAdd(&lcur[ed & 127], 1);
        csr[pos] = (int)(ed >> 7);
    }
}

// ---------------- GEMM + fused alpha dots ----------------
// NPT=4 nodes per thread. COLS=128 -> fp8 e4m3 output; COLS=32 -> bf16 output.

template<int COLS, int HEADS>
__global__ __launch_bounds__(256) void gemm_alpha_kernel(
    const float* __restrict__ x, const float* __restrict__ W,
    const float* __restrict__ a_src, const float* __restrict__ a_dst,
    uint* __restrict__ hq, float* __restrict__ as_out,
    float* __restrict__ ad_out, int n)
{
    constexpr int K = 128;
    constexpr int CPT = COLS / 8;
    constexpr int NPT = 4;
    constexpr int DIM = COLS / HEADS;
    constexpr int TPH = DIM / CPT;
    constexpr int NSLOT = COLS / 4;
    __shared__ float4 WL[K * NSLOT];

    int t = threadIdx.x;
    for (int idx = t * 4; idx < K * COLS; idx += 1024) {
        float4 w = *(const float4*)(W + idx);
        int k = idx / COLS, c = idx % COLS;
        int slot = c >> 2;
        if (COLS == 128) slot = (slot >> 2) | ((slot & 3) << 3);
        WL[k * NSLOT + slot] = w;
    }
    __syncthreads();

    int m_ = t & 7;
    int node0 = blockIdx.x * (32 * NPT) + (t >> 3) * NPT;
    if (node0 >= n) return;
    int c0 = m_ * CPT;

    const float* xr[NPT];
#pragma unroll
    for (int i = 0; i < NPT; i++) xr[i] = x + (size_t)min(node0 + i, n - 1) * K;

    float acc[NPT][CPT];
#pragma unroll
    for (int i = 0; i < NPT; i++)
#pragma unroll
        for (int q = 0; q < CPT; q++) acc[i][q] = 0.f;

    for (int k4 = 0; k4 < K; k4 += 4) {
        float4 xv[NPT];
#pragma unroll
        for (int i = 0; i < NPT; i++) xv[i] = *(const float4*)(xr[i] + k4);
#pragma unroll
        for (int kk = 0; kk < 4; kk++) {
#pragma unroll
            for (int j = 0; j < CPT / 4; j++) {
                int slot = (COLS == 128) ? (m_ | (j << 3)) : m_;
                float4 w = WL[(k4 + kk) * NSLOT + slot];
#pragma unroll
                for (int i = 0; i < NPT; i++) {
                    float xa = f4get(xv[i], kk);
                    acc[i][j*4+0] += xa * w.x;
                    acc[i][j*4+1] += xa * w.y;
                    acc[i][j*4+2] += xa * w.z;
                    acc[i][j*4+3] += xa * w.w;
                }
            }
        }
    }

    int head = c0 / DIM, lc = c0 - head * DIM;
    float asc[CPT], adc[CPT];
#pragma unroll
    for (int q = 0; q < CPT; q++) {
        asc[q] = a_src[head * DIM + lc + q];
        adc[q] = a_dst[head * DIM + lc + q];
    }

#pragma unroll
    for (int i = 0; i < NPT; i++) {
        int node = node0 + i;
        if (node >= n) break;
        if constexpr (COLS == 128) {
            uint wds[4];
#pragma unroll
            for (int j = 0; j < 4; j++) {
                int u = 0;
                u = __builtin_amdgcn_cvt_pk_fp8_f32(acc[i][j*4+0], acc[i][j*4+1], u, false);
                u = __builtin_amdgcn_cvt_pk_fp8_f32(acc[i][j*4+2], acc[i][j*4+3], u, true);
                wds[j] = (uint)u;
            }
            *(uint4*)(hq + (size_t)node * 32 + m_ * 4) = make_uint4(wds[0], wds[1], wds[2], wds[3]);
        } else {
            uint w0 = packbf(acc[i][0], acc[i][1]);
            uint w1 = packbf(acc[i][2], acc[i][3]);
            *(uint2*)(hq + (size_t)node * 16 + m_ * 2) = make_uint2(w0, w1);
        }
        float ps = 0.f, pd = 0.f;
#pragma unroll
        for (int q = 0; q < CPT; q++) {
            ps += acc[i][q] * asc[q];
            pd += acc[i][q] * adc[q];
        }
#pragma unroll
        for (int off = 1; off < TPH; off <<= 1) {
            ps += __shfl_xor(ps, off);
            pd += __shfl_xor(pd, off);
        }
        if ((m_ & (TPH - 1)) == 0) {
            as_out[node * HEADS + head] = ps;
            ad_out[node * HEADS + head] = pd;
        }
    }
}

// ---------------- Layer-1 aggregation (fp8 gather) ----------------
// One wave per node, 4 waves/block (R5 sync structure: barriers uniform via
// block-max chunk count). Consume: 8 edge-groups x 8 lanes; lane loads uint4
// = 16 fp8 dims (dims 16l..16l+15), so one group covers the whole 128B row
// and the wave holds 8 edges in flight per iteration. End: 3-round shfl_xor
// reduction across groups, once per node.

__global__ __launch_bounds__(256) void agg1_kernel(
    const float4* __restrict__ as1, const float4* __restrict__ ad1,
    const uint* __restrict__ h1q, const int* __restrict__ rowptr,
    const int* __restrict__ csr, const float* __restrict__ b1,
    float* __restrict__ hout, int n)
{
    __shared__ int   sIdx[4][64];
    __shared__ float sEx[4][64][4];
    __shared__ int   mxch;

    int t = threadIdx.x;
    int w = t >> 6, tw = t & 63;
    int g = tw >> 3, l = tw & 7;   // 8 groups x 8 lanes
    int head = l >> 1;             // dims 16l..16l+15 -> head = 16l/32
    int node = blockIdx.x * 4 + w;
    if (t == 0) mxch = 0;
    bool valid = node < n;
    int nv = valid ? node : 0;

    float4 adv = ad1[nv];
    int rp = rowptr[nv], re = valid ? rowptr[nv + 1] : rp;
    __syncthreads();
    if (tw == 0) atomicMax(&mxch, (re - rp + 63) >> 6);
    __syncthreads();
    int mx = mxch;

    float acc[16];
#pragma unroll
    for (int i = 0; i < 16; i++) acc[i] = 0.f;
    float den = 0.f;

    for (int c = 0; c < mx; ++c) {
        int base = rp + c * 64;
        int cnt = min(64, re - base);
        if (tw < cnt) {
            int s = csr[base + tw];
            sIdx[w][tw] = s;
            float4 av = as1[s];
            sEx[w][tw][0] = __expf(LRELU(av.x + adv.x));
            sEx[w][tw][1] = __expf(LRELU(av.y + adv.y));
            sEx[w][tw][2] = __expf(LRELU(av.z + adv.z));
            sEx[w][tw][3] = __expf(LRELU(av.w + adv.w));
        }
        __syncthreads();
#pragma unroll 2
        for (int e = g; e < cnt; e += 8) {
            int s = sIdx[w][e];
            float ex = sEx[w][e][head];
            den += ex;
            uint4 u = *(const uint4*)(h1q + ((size_t)s << 5) + (l << 2));
            uint ua[4] = {u.x, u.y, u.z, u.w};
#pragma unroll
            for (int j = 0; j < 4; j++) {
                auto p0 = __builtin_amdgcn_cvt_pk_f32_fp8(ua[j], false);
                auto p1 = __builtin_amdgcn_cvt_pk_f32_fp8(ua[j], true);
                acc[j*4+0] += ex * p0[0]; acc[j*4+1] += ex * p0[1];
                acc[j*4+2] += ex * p1[0]; acc[j*4+3] += ex * p1[1];
            }
        }
        __syncthreads();
    }

    // reduce across the 8 groups (xor on bits 3,4,5 of lane id)
#pragma unroll
    for (int i = 0; i < 16; i++) {
        acc[i] += __shfl_xor(acc[i], 8);
        acc[i] += __shfl_xor(acc[i], 16);
        acc[i] += __shfl_xor(acc[i], 32);
    }
    den += __shfl_xor(den, 8);
    den += __shfl_xor(den, 16);
    den += __shfl_xor(den, 32);

    if (valid) {
        // self loop (all lanes hold identical reduced copies; add uniformly)
        float4 asv = as1[node];
        float ex = __expf(LRELU(f4get(asv, head) + f4get(adv, head)));
        den += ex;
        uint4 u = *(const uint4*)(h1q + ((size_t)node << 5) + (l << 2));
        uint ua[4] = {u.x, u.y, u.z, u.w};
#pragma unroll
        for (int j = 0; j < 4; j++) {
            auto p0 = __builtin_amdgcn_cvt_pk_f32_fp8(ua[j], false);
            auto p1 = __builtin_amdgcn_cvt_pk_f32_fp8(ua[j], true);
            acc[j*4+0] += ex * p0[0]; acc[j*4+1] += ex * p0[1];
            acc[j*4+2] += ex * p1[0]; acc[j*4+3] += ex * p1[1];
        }
        if (g == 0) {
            float inv = 1.f / (den + 1e-16f);
            const float4* b4 = (const float4*)b1;
#pragma unroll
            for (int j = 0; j < 4; j++) {
                float4 bv = b4[(l << 2) + j];
                float4 o;
                o.x = fmaxf(acc[j*4+0] * inv + bv.x, 0.f);
                o.y = fmaxf(acc[j*4+1] * inv + bv.y, 0.f);
                o.z = fmaxf(acc[j*4+2] * inv + bv.z, 0.f);
                o.w = fmaxf(acc[j*4+3] * inv + bv.w, 0.f);
                ((float4*)hout)[(size_t)node * 32 + (l << 2) + j] = o;
            }
        }
    }
}

// ---------------- Layer-2 aggregation (bf16x2 gather, mean over heads) --------
// Same structure: 8 groups x 8 lanes; lane loads uint2 = 4 bf16 dims
// (dims 4l..4l+3); group covers the 64B row; 8 edges in flight per wave.

__global__ __launch_bounds__(256) void agg2_kernel(
    const float2* __restrict__ as2, const float2* __restrict__ ad2,
    const uint* __restrict__ h2q, const int* __restrict__ rowptr,
    const int* __restrict__ csr, const float* __restrict__ b2,
    float* __restrict__ hf, int n)
{
    __shared__ int   sIdx[4][64];
    __shared__ float sEx[4][64][2];
    __shared__ int   mxch;

    int t = threadIdx.x;
    int w = t >> 6, tw = t & 63;
    int g = tw >> 3, l = tw & 7;   // 8 groups x 8 lanes
    int head = l >> 2;             // dims 4l..4l+3 -> head = 4l/16
    int node = blockIdx.x * 4 + w;
    if (t == 0) mxch = 0;
    bool valid = node < n;
    int nv = valid ? node : 0;

    float2 adv = ad2[nv];
    float adh = head ? adv.y : adv.x;
    int rp = rowptr[nv], re = valid ? rowptr[nv + 1] : rp;
    __syncthreads();
    if (tw == 0) atomicMax(&mxch, (re - rp + 63) >> 6);
    __syncthreads();
    int mx = mxch;

    float acc[4] = {0.f, 0.f, 0.f, 0.f};
    float den = 0.f;

    for (int c = 0; c < mx; ++c) {
        int base = rp + c * 64;
        int cnt = min(64, re - base);
        if (tw < cnt) {
            int s = csr[base + tw];
            sIdx[w][tw] = s;
            float2 av = as2[s];
            sEx[w][tw][0] = __expf(LRELU(av.x + adv.x));
            sEx[w][tw][1] = __expf(LRELU(av.y + adv.y));
        }
        __syncthreads();
#pragma unroll 2
        for (int e = g; e < cnt; e += 8) {
            int s = sIdx[w][e];
            float ex = sEx[w][e][head];
            den += ex;
            uint2 u = *(const uint2*)(h2q + ((size_t)s << 4) + (l << 1));
            acc[0] += ex * bflo(u.x); acc[1] += ex * bfhi(u.x);
            acc[2] += ex * bflo(u.y); acc[3] += ex * bfhi(u.y);
        }
        __syncthreads();
    }

#pragma unroll
    for (int i = 0; i < 4; i++) {
        acc[i] += __shfl_xor(acc[i], 8);
        acc[i] += __shfl_xor(acc[i], 16);
        acc[i] += __shfl_xor(acc[i], 32);
    }
    den += __shfl_xor(den, 8);
    den += __shfl_xor(den, 16);
    den += __shfl_xor(den, 32);

    if (valid) {
        float2 asv = as2[node];
        float ash = head ? asv.y : asv.x;
        float ex = __expf(LRELU(ash + adh));
        den += ex;
        uint2 u = *(const uint2*)(h2q + ((size_t)node << 4) + (l << 1));
        acc[0] += ex * bflo(u.x); acc[1] += ex * bfhi(u.x);
        acc[2] += ex * bflo(u.y); acc[3] += ex * bfhi(u.y);

        float inv = 1.f / (den + 1e-16f);
        float v0 = acc[0] * inv, v1 = acc[1] * inv, v2 = acc[2] * inv, v3 = acc[3] * inv;
        // mean over heads: head0 dims d at lane l, head1 dims 16+d at lane l+4
        float o0 = 0.5f * (v0 + __shfl_xor(v0, 4));
        float o1 = 0.5f * (v1 + __shfl_xor(v1, 4));
        float o2 = 0.5f * (v2 + __shfl_xor(v2, 4));
        float o3 = 0.5f * (v3 + __shfl_xor(v3, 4));
        if (g == 0 && l < 4) {
            float4 o;
            o.x = o0 + b2[4*l+0]; o.y = o1 + b2[4*l+1];
            o.z = o2 + b2[4*l+2]; o.w = o3 + b2[4*l+3];
            *(float4*)(hf + (size_t)node * 16 + 4 * l) = o;
        }
    }
}

// ---------------- Pooling + FC ----------------

__global__ __launch_bounds__(256) void pool_kernel(
    const float* __restrict__ hf, const int* __restrict__ batch,
    float* __restrict__ sums, float* __restrict__ counts, int n)
{
    int t = threadIdx.x;
    int d = t & 15, j = t >> 4;
    int base = blockIdx.x * 256 + j * 16;
    float run = 0.f, cnt = 0.f;
    int cg = -1;
    for (int i = 0; i < 16; ++i) {
        int nn = base + i;
        if (nn >= n) break;
        int g = batch[nn];
        if (g != cg) {
            if (cg >= 0) { atomicAdd(&sums[cg * 16 + d], run); if (d == 0) atomicAdd(&counts[cg], cnt); }
            cg = g; run = 0.f; cnt = 0.f;
        }
        run += hf[(size_t)nn * 16 + d];
        cnt += 1.f;
    }
    if (cg >= 0) { atomicAdd(&sums[cg * 16 + d], run); if (d == 0) atomicAdd(&counts[cg], cnt); }
}

__global__ void final_kernel(const float* __restrict__ sums, const float* __restrict__ counts,
                             const float* __restrict__ fcW, const float* __restrict__ fcb,
                             float* __restrict__ out, int G)
{
    int g = blockIdx.x * 64 + threadIdx.x;
    if (g < G) {
        float c = fmaxf(counts[g], 1.f);
        float s = 0.f;
        for (int dd = 0; dd < 16; ++dd) s += (sums[g * 16 + dd] / c) * fcW[dd];
        out[g] = s + fcb[0];
    }
}

// ---------------- launch ----------------

extern "C" void kernel_launch(void* const* d_in, const int* in_sizes, int n_in,
                              void* d_out, int out_size, void* d_ws, size_t ws_size,
                              hipStream_t stream)
{
    const float* x      = (const float*)d_in[0];
    const int*   ei     = (const int*)d_in[1];
    const int*   batch  = (const int*)d_in[2];
    const float* W1     = (const float*)d_in[3];
    const float* a_src1 = (const float*)d_in[4];
    const float* a_dst1 = (const float*)d_in[5];
    const float* b1     = (const float*)d_in[6];
    const float* W2     = (const float*)d_in[7];
    const float* a_src2 = (const float*)d_in[8];
    const float* a_dst2 = (const float*)d_in[9];
    const float* b2     = (const float*)d_in[10];
    const float* fcW    = (const float*)d_in[11];
    const float* fcb    = (const float*)d_in[12];
    float* out = (float*)d_out;

    int n = in_sizes[0] / 128;
    int E = in_sizes[1] / 2;
    int G = out_size;
    const int* srcA = ei;
    const int* dstA = ei + E;

    int nb = (n + (1 << CSR_SHIFT) - 1) >> CSR_SHIFT;
    int chunk = (E + CSR_NBLK - 1) / CSR_NBLK;

    char* p = (char*)d_ws;
    auto alloc = [&](size_t bytes) { char* r = p; p += (bytes + 255) & ~(size_t)255; return r; };
    int*   blockCntT  = (int*)alloc((size_t)nb * CSR_NBLK * 4);
    int*   tot        = (int*)alloc((size_t)nb * 4);
    int*   bucketBase = (int*)alloc((size_t)(nb + 1) * 4);
    int*   rowptr     = (int*)alloc((size_t)(n + 1) * 4);
    int*   csr        = (int*)alloc((size_t)E * 4);
    uint*  h1q        = (uint*)alloc((size_t)n * 32 * 4);    // fp8 x4 per uint
    float* as1        = (float*)alloc((size_t)n * 16);
    float* ad1        = (float*)alloc((size_t)n * 16);
    float* hrelu      = (float*)alloc((size_t)n * 128 * 4);
    uint*  h2q        = (uint*)alloc((size_t)n * 16 * 4);    // bf16 x2 per uint
    float* as2        = (float*)alloc((size_t)n * 8);
    float* ad2        = (float*)alloc((size_t)n * 8);
    float* hf         = (float*)alloc((size_t)n * 16 * 4);
    float* sums       = (float*)alloc((size_t)G * 16 * 4 + (size_t)G * 4);
    float* counts     = sums + G * 16;

    // edge staging buffer aliases hrelu; consumed by local_csr before agg1 writes.
    uint* ebuf = (uint*)hrelu;

    hipMemsetAsync(sums, 0, (size_t)G * 16 * 4 + (size_t)G * 4, stream);

    bucket_count_kernel<<<CSR_NBLK, 256, 0, stream>>>(dstA, E, chunk, nb, blockCntT);
    row_scan_kernel<<<nb, 512, 0, stream>>>(blockCntT, tot);
    total_scan_kernel<<<1, 1024, 0, stream>>>(tot, nb, bucketBase);
    bucket_scatter_kernel<<<CSR_NBLK, 256, 0, stream>>>(srcA, dstA, E, chunk, nb,
                                                        blockCntT, bucketBase, ebuf);
    local_csr_kernel<<<nb, 256, 0, stream>>>(ebuf, bucketBase, n, E, rowptr, csr);

    int gb = (n + 127) / 128;
    gemm_alpha_kernel<128, 4><<<gb, 256, 0, stream>>>(x, W1, a_src1, a_dst1, h1q, as1, ad1, n);
    agg1_kernel<<<(n + 3) / 4, 256, 0, stream>>>((const float4*)as1, (const float4*)ad1,
                                                 h1q, rowptr, csr, b1, hrelu, n);
    gemm_alpha_kernel<32, 2><<<gb, 256, 0, stream>>>(hrelu, W2, a_src2, a_dst2, h2q, as2, ad2, n);
    agg2_kernel<<<(n + 3) / 4, 256, 0, stream>>>((const float2*)as2, (const float2*)ad2,
                                                 h2q, rowptr, csr, b2, hf, n);
    pool_kernel<<<(n + 255) / 256, 256, 0, stream>>>(hf, batch, sums, counts, n);
    final_kernel<<<1, 64, 0, stream>>>(sums, counts, fcW, fcb, out, G);
}

// Round 8
// 195.851 us; speedup vs baseline: 1.0751x; 1.0685x over previous
//
#include <hip/hip_runtime.h>

#define LRELU(x) ((x) > 0.f ? (x) : 0.2f*(x))
typedef unsigned int uint;

__device__ inline unsigned short f2bf(float f) {
    union { float f; unsigned u; } v; v.f = f;
    unsigned r = v.u + 0x7FFF + ((v.u >> 16) & 1);
    return (unsigned short)(r >> 16);
}
__device__ inline uint packbf(float a, float b) {
    return (uint)f2bf(a) | ((uint)f2bf(b) << 16);
}
__device__ inline float bflo(uint u){ union{uint u; float f;}v; v.u = u<<16; return v.f; }
__device__ inline float bfhi(uint u){ union{uint u; float f;}v; v.u = u & 0xFFFF0000u; return v.f; }
__device__ inline float f4get(const float4& v, int i) {
    return i==0 ? v.x : i==1 ? v.y : i==2 ? v.z : v.w;
}

// ---------------- CSR build: atomic-free two-level bucket sort ----------------
// ebuf entries packed: (src << 7) | (dst & 127)

#define CSR_SHIFT 7
#define CSR_NBLK  512

__global__ __launch_bounds__(256) void bucket_count_kernel(
    const int* __restrict__ dst, int E, int chunk, int nb,
    int* __restrict__ blockCntT)
{
    __shared__ int cnt[1024];
    int t = threadIdx.x, k = blockIdx.x;
    for (int i = t; i < nb; i += 256) cnt[i] = 0;
    __syncthreads();
    int e0 = k * chunk, e1 = min(e0 + chunk, E);
    for (int e = e0 + t; e < e1; e += 256)
        atomicAdd(&cnt[dst[e] >> CSR_SHIFT], 1);
    __syncthreads();
    for (int b = t; b < nb; b += 256)
        blockCntT[b * CSR_NBLK + k] = cnt[b];
}

__global__ __launch_bounds__(512) void row_scan_kernel(
    int* __restrict__ blockCntT, int* __restrict__ tot)
{
    __shared__ int sm[512];
    int b = blockIdx.x, t = threadIdx.x;
    int* row = blockCntT + b * CSR_NBLK;
    int v = row[t];
    sm[t] = v;
    __syncthreads();
    for (int off = 1; off < 512; off <<= 1) {
        int u = (t >= off) ? sm[t - off] : 0;
        __syncthreads(); sm[t] += u; __syncthreads();
    }
    row[t] = sm[t] - v;            // exclusive within bucket
    if (t == 511) tot[b] = sm[511];
}

__global__ __launch_bounds__(1024) void total_scan_kernel(
    const int* __restrict__ tot, int nb, int* __restrict__ bucketBase)
{
    __shared__ int sm[1024];
    int t = threadIdx.x;
    int v = (t < nb) ? tot[t] : 0;
    sm[t] = v;
    __syncthreads();
    for (int off = 1; off < 1024; off <<= 1) {
        int u = (t >= off) ? sm[t - off] : 0;
        __syncthreads(); sm[t] += u; __syncthreads();
    }
    if (t < nb) bucketBase[t] = sm[t] - v;
    if (t == 1023) bucketBase[nb] = sm[1023];
}

__global__ __launch_bounds__(256) void bucket_scatter_kernel(
    const int* __restrict__ src, const int* __restrict__ dst, int E, int chunk, int nb,
    const int* __restrict__ blockCntT, const int* __restrict__ bucketBase,
    uint* __restrict__ ebuf)
{
    __shared__ int cur[1024];
    int t = threadIdx.x, k = blockIdx.x;
    for (int b = t; b < nb; b += 256)
        cur[b] = bucketBase[b] + blockCntT[b * CSR_NBLK + k];
    __syncthreads();
    int e0 = k * chunk, e1 = min(e0 + chunk, E);
    for (int e = e0 + t; e < e1; e += 256) {
        int d = dst[e], s_ = src[e];
        int pos = atomicAdd(&cur[d >> CSR_SHIFT], 1);
        ebuf[pos] = ((uint)s_ << 7) | (uint)(d & 127);
    }
}

__global__ __launch_bounds__(256) void local_csr_kernel(
    const uint* __restrict__ ebuf, const int* __restrict__ bucketBase,
    int n, int E, int* __restrict__ rowptr, int* __restrict__ csr)
{
    __shared__ int lbase[1 << CSR_SHIFT];
    __shared__ int lcur[1 << CSR_SHIFT];
    __shared__ int ldeg[1 << CSR_SHIFT];
    int b = blockIdx.x, t = threadIdx.x;
    int n0 = b << CSR_SHIFT;
    int base = bucketBase[b], end = bucketBase[b + 1];
    if (t < (1 << CSR_SHIFT)) ldeg[t] = 0;
    __syncthreads();
    for (int e = base + t; e < end; e += 256)
        atomicAdd(&ldeg[ebuf[e] & 127], 1);
    __syncthreads();
    if (t == 0) {
        int run = base;
        for (int i = 0; i < (1 << CSR_SHIFT); ++i) {
            lbase[i] = run; lcur[i] = run; run += ldeg[i];
        }
    }
    __syncthreads();
    int node = n0 + t;
    if (t < (1 << CSR_SHIFT) && node < n) rowptr[node] = lbase[t];
    if (b == 0 && t == 0) rowptr[n] = E;
    for (int e = base + t; e < end; e += 256) {
        uint ed = ebuf[e];
        int pos = atomicAdd(&lcur[ed & 127], 1);
        csr[pos] = (int)(ed >> 7);
    }
}

// ---------------- GEMM + fused alpha dots ----------------
// NPT=4 nodes per thread. COLS=128 -> fp8 e4m3 output; COLS=32 -> bf16 output.

template<int COLS, int HEADS>
__global__ __launch_bounds__(256) void gemm_alpha_kernel(
    const float* __restrict__ x, const float* __restrict__ W,
    const float* __restrict__ a_src, const float* __restrict__ a_dst,
    uint* __restrict__ hq, float* __restrict__ as_out,
    float* __restrict__ ad_out, int n)
{
    constexpr int K = 128;
    constexpr int CPT = COLS / 8;
    constexpr int NPT = 4;
    constexpr int DIM = COLS / HEADS;
    constexpr int TPH = DIM / CPT;
    constexpr int NSLOT = COLS / 4;
    __shared__ float4 WL[K * NSLOT];

    int t = threadIdx.x;
    for (int idx = t * 4; idx < K * COLS; idx += 1024) {
        float4 w = *(const float4*)(W + idx);
        int k = idx / COLS, c = idx % COLS;
        int slot = c >> 2;
        if (COLS == 128) slot = (slot >> 2) | ((slot & 3) << 3);
        WL[k * NSLOT + slot] = w;
    }
    __syncthreads();

    int m_ = t & 7;
    int node0 = blockIdx.x * (32 * NPT) + (t >> 3) * NPT;
    if (node0 >= n) return;
    int c0 = m_ * CPT;

    const float* xr[NPT];
#pragma unroll
    for (int i = 0; i < NPT; i++) xr[i] = x + (size_t)min(node0 + i, n - 1) * K;

    float acc[NPT][CPT];
#pragma unroll
    for (int i = 0; i < NPT; i++)
#pragma unroll
        for (int q = 0; q < CPT; q++) acc[i][q] = 0.f;

    for (int k4 = 0; k4 < K; k4 += 4) {
        float4 xv[NPT];
#pragma unroll
        for (int i = 0; i < NPT; i++) xv[i] = *(const float4*)(xr[i] + k4);
#pragma unroll
        for (int kk = 0; kk < 4; kk++) {
#pragma unroll
            for (int j = 0; j < CPT / 4; j++) {
                int slot = (COLS == 128) ? (m_ | (j << 3)) : m_;
                float4 w = WL[(k4 + kk) * NSLOT + slot];
#pragma unroll
                for (int i = 0; i < NPT; i++) {
                    float xa = f4get(xv[i], kk);
                    acc[i][j*4+0] += xa * w.x;
                    acc[i][j*4+1] += xa * w.y;
                    acc[i][j*4+2] += xa * w.z;
                    acc[i][j*4+3] += xa * w.w;
                }
            }
        }
    }

    int head = c0 / DIM, lc = c0 - head * DIM;
    float asc[CPT], adc[CPT];
#pragma unroll
    for (int q = 0; q < CPT; q++) {
        asc[q] = a_src[head * DIM + lc + q];
        adc[q] = a_dst[head * DIM + lc + q];
    }

#pragma unroll
    for (int i = 0; i < NPT; i++) {
        int node = node0 + i;
        if (node >= n) break;
        if constexpr (COLS == 128) {
            uint wds[4];
#pragma unroll
            for (int j = 0; j < 4; j++) {
                int u = 0;
                u = __builtin_amdgcn_cvt_pk_fp8_f32(acc[i][j*4+0], acc[i][j*4+1], u, false);
                u = __builtin_amdgcn_cvt_pk_fp8_f32(acc[i][j*4+2], acc[i][j*4+3], u, true);
                wds[j] = (uint)u;
            }
            *(uint4*)(hq + (size_t)node * 32 + m_ * 4) = make_uint4(wds[0], wds[1], wds[2], wds[3]);
        } else {
            uint w0 = packbf(acc[i][0], acc[i][1]);
            uint w1 = packbf(acc[i][2], acc[i][3]);
            *(uint2*)(hq + (size_t)node * 16 + m_ * 2) = make_uint2(w0, w1);
        }
        float ps = 0.f, pd = 0.f;
#pragma unroll
        for (int q = 0; q < CPT; q++) {
            ps += acc[i][q] * asc[q];
            pd += acc[i][q] * adc[q];
        }
#pragma unroll
        for (int off = 1; off < TPH; off <<= 1) {
            ps += __shfl_xor(ps, off);
            pd += __shfl_xor(pd, off);
        }
        if ((m_ & (TPH - 1)) == 0) {
            as_out[node * HEADS + head] = ps;
            ad_out[node * HEADS + head] = pd;
        }
    }
}

// ---------------- Layer-1 aggregation (flat, fp8 gather) ----------------
// One wave per node; NO LDS, NO barriers, waves fully independent.
// 8 edge-groups x 8 lanes: group g owns edges rp+g, rp+g+8, ...
// Lane (g,l): head = l>>1; loads its edge's alpha scalar (4B) + its 16-dim
// fp8 slice (uint4) of the message row; 1 exp + 16 fma per edge.
// End: 3-round shfl_xor reduction across groups (same l => same dims/head).

__global__ __launch_bounds__(256) void agg1_kernel(
    const float* __restrict__ as1f, const float* __restrict__ ad1f,
    const uint* __restrict__ h1q, const int* __restrict__ rowptr,
    const int* __restrict__ csr, const float* __restrict__ b1,
    float* __restrict__ hout, int n)
{
    int t = threadIdx.x;
    int w = t >> 6, tw = t & 63;
    int g = tw >> 3, l = tw & 7;   // 8 groups x 8 lanes
    int head = l >> 1;             // dims 16l..16l+15 -> head
    int node = blockIdx.x * 4 + w;
    if (node >= n) return;

    float adh = ad1f[node * 4 + head];
    int rp = rowptr[node], re = rowptr[node + 1];

    float acc[16];
#pragma unroll
    for (int i = 0; i < 16; i++) acc[i] = 0.f;
    float den = 0.f;

#pragma unroll 2
    for (int e = rp + g; e < re; e += 8) {
        int s = csr[e];
        float a = as1f[s * 4 + head];
        uint4 u = *(const uint4*)(h1q + ((size_t)s << 5) + (l << 2));
        float ex = __expf(LRELU(a + adh));
        den += ex;
        uint ua[4] = {u.x, u.y, u.z, u.w};
#pragma unroll
        for (int j = 0; j < 4; j++) {
            auto p0 = __builtin_amdgcn_cvt_pk_f32_fp8(ua[j], false);
            auto p1 = __builtin_amdgcn_cvt_pk_f32_fp8(ua[j], true);
            acc[j*4+0] += ex * p0[0]; acc[j*4+1] += ex * p0[1];
            acc[j*4+2] += ex * p1[0]; acc[j*4+3] += ex * p1[1];
        }
    }

    if (g == 0) {   // self loop, counted once (pre-reduction)
        float a = as1f[node * 4 + head];
        float ex = __expf(LRELU(a + adh));
        den += ex;
        uint4 u = *(const uint4*)(h1q + ((size_t)node << 5) + (l << 2));
        uint ua[4] = {u.x, u.y, u.z, u.w};
#pragma unroll
        for (int j = 0; j < 4; j++) {
            auto p0 = __builtin_amdgcn_cvt_pk_f32_fp8(ua[j], false);
            auto p1 = __builtin_amdgcn_cvt_pk_f32_fp8(ua[j], true);
            acc[j*4+0] += ex * p0[0]; acc[j*4+1] += ex * p0[1];
            acc[j*4+2] += ex * p1[0]; acc[j*4+3] += ex * p1[1];
        }
    }

    // reduce across the 8 groups (lane-id bits 3,4,5)
#pragma unroll
    for (int i = 0; i < 16; i++) {
        acc[i] += __shfl_xor(acc[i], 8);
        acc[i] += __shfl_xor(acc[i], 16);
        acc[i] += __shfl_xor(acc[i], 32);
    }
    den += __shfl_xor(den, 8);
    den += __shfl_xor(den, 16);
    den += __shfl_xor(den, 32);

    if (g == 0) {
        float inv = 1.f / (den + 1e-16f);
        const float4* b4 = (const float4*)b1;
#pragma unroll
        for (int j = 0; j < 4; j++) {
            float4 bv = b4[(l << 2) + j];
            float4 o;
            o.x = fmaxf(acc[j*4+0] * inv + bv.x, 0.f);
            o.y = fmaxf(acc[j*4+1] * inv + bv.y, 0.f);
            o.z = fmaxf(acc[j*4+2] * inv + bv.z, 0.f);
            o.w = fmaxf(acc[j*4+3] * inv + bv.w, 0.f);
            ((float4*)hout)[(size_t)node * 32 + (l << 2) + j] = o;
        }
    }
}

// ---------------- Layer-2 aggregation (flat, bf16 gather, head-mean) ----------
// Same flat structure: 8 groups x 8 lanes; lane covers dims 4l..4l+3 (uint2);
// head = l>>2. After group reduction, head-mean pairs lane l with l^4.

__global__ __launch_bounds__(256) void agg2_kernel(
    const float* __restrict__ as2f, const float* __restrict__ ad2f,
    const uint* __restrict__ h2q, const int* __restrict__ rowptr,
    const int* __restrict__ csr, const float* __restrict__ b2,
    float* __restrict__ hf, int n)
{
    int t = threadIdx.x;
    int w = t >> 6, tw = t & 63;
    int g = tw >> 3, l = tw & 7;
    int head = l >> 2;
    int node = blockIdx.x * 4 + w;
    if (node >= n) return;

    float adh = ad2f[node * 2 + head];
    int rp = rowptr[node], re = rowptr[node + 1];

    float acc[4] = {0.f, 0.f, 0.f, 0.f};
    float den = 0.f;

#pragma unroll 2
    for (int e = rp + g; e < re; e += 8) {
        int s = csr[e];
        float a = as2f[s * 2 + head];
        uint2 u = *(const uint2*)(h2q + ((size_t)s << 4) + (l << 1));
        float ex = __expf(LRELU(a + adh));
        den += ex;
        acc[0] += ex * bflo(u.x); acc[1] += ex * bfhi(u.x);
        acc[2] += ex * bflo(u.y); acc[3] += ex * bfhi(u.y);
    }

    if (g == 0) {   // self loop
        float a = as2f[node * 2 + head];
        float ex = __expf(LRELU(a + adh));
        den += ex;
        uint2 u = *(const uint2*)(h2q + ((size_t)node << 4) + (l << 1));
        acc[0] += ex * bflo(u.x); acc[1] += ex * bfhi(u.x);
        acc[2] += ex * bflo(u.y); acc[3] += ex * bfhi(u.y);
    }

#pragma unroll
    for (int i = 0; i < 4; i++) {
        acc[i] += __shfl_xor(acc[i], 8);
        acc[i] += __shfl_xor(acc[i], 16);
        acc[i] += __shfl_xor(acc[i], 32);
    }
    den += __shfl_xor(den, 8);
    den += __shfl_xor(den, 16);
    den += __shfl_xor(den, 32);

    float inv = 1.f / (den + 1e-16f);
    float v0 = acc[0] * inv, v1 = acc[1] * inv, v2 = acc[2] * inv, v3 = acc[3] * inv;
    // mean over heads: lane l (head0, dims 4l..) pairs with lane l^4 (head1, dims 16+4l..)
    float o0 = 0.5f * (v0 + __shfl_xor(v0, 4));
    float o1 = 0.5f * (v1 + __shfl_xor(v1, 4));
    float o2 = 0.5f * (v2 + __shfl_xor(v2, 4));
    float o3 = 0.5f * (v3 + __shfl_xor(v3, 4));
    if (g == 0 && l < 4) {
        float4 o;
        o.x = o0 + b2[4*l+0]; o.y = o1 + b2[4*l+1];
        o.z = o2 + b2[4*l+2]; o.w = o3 + b2[4*l+3];
        *(float4*)(hf + (size_t)node * 16 + 4 * l) = o;
    }
}

// ---------------- Pooling + FC ----------------

__global__ __launch_bounds__(256) void pool_kernel(
    const float* __restrict__ hf, const int* __restrict__ batch,
    float* __restrict__ sums, float* __restrict__ counts, int n)
{
    int t = threadIdx.x;
    int d = t & 15, j = t >> 4;
    int base = blockIdx.x * 256 + j * 16;
    float run = 0.f, cnt = 0.f;
    int cg = -1;
    for (int i = 0; i < 16; ++i) {
        int nn = base + i;
        if (nn >= n) break;
        int g = batch[nn];
        if (g != cg) {
            if (cg >= 0) { atomicAdd(&sums[cg * 16 + d], run); if (d == 0) atomicAdd(&counts[cg], cnt); }
            cg = g; run = 0.f; cnt = 0.f;
        }
        run += hf[(size_t)nn * 16 + d];
        cnt += 1.f;
    }
    if (cg >= 0) { atomicAdd(&sums[cg * 16 + d], run); if (d == 0) atomicAdd(&counts[cg], cnt); }
}

__global__ void final_kernel(const float* __restrict__ sums, const float* __restrict__ counts,
                             const float* __restrict__ fcW, const float* __restrict__ fcb,
                             float* __restrict__ out, int G)
{
    int g = blockIdx.x * 64 + threadIdx.x;
    if (g < G) {
        float c = fmaxf(counts[g], 1.f);
        float s = 0.f;
        for (int dd = 0; dd < 16; ++dd) s += (sums[g * 16 + dd] / c) * fcW[dd];
        out[g] = s + fcb[0];
    }
}

// ---------------- launch ----------------

extern "C" void kernel_launch(void* const* d_in, const int* in_sizes, int n_in,
                              void* d_out, int out_size, void* d_ws, size_t ws_size,
                              hipStream_t stream)
{
    const float* x      = (const float*)d_in[0];
    const int*   ei     = (const int*)d_in[1];
    const int*   batch  = (const int*)d_in[2];
    const float* W1     = (const float*)d_in[3];
    const float* a_src1 = (const float*)d_in[4];
    const float* a_dst1 = (const float*)d_in[5];
    const float* b1     = (const float*)d_in[6];
    const float* W2     = (const float*)d_in[7];
    const float* a_src2 = (const float*)d_in[8];
    const float* a_dst2 = (const float*)d_in[9];
    const float* b2     = (const float*)d_in[10];
    const float* fcW    = (const float*)d_in[11];
    const float* fcb    = (const float*)d_in[12];
    float* out = (float*)d_out;

    int n = in_sizes[0] / 128;
    int E = in_sizes[1] / 2;
    int G = out_size;
    const int* srcA = ei;
    const int* dstA = ei + E;

    int nb = (n + (1 << CSR_SHIFT) - 1) >> CSR_SHIFT;
    int chunk = (E + CSR_NBLK - 1) / CSR_NBLK;

    char* p = (char*)d_ws;
    auto alloc = [&](size_t bytes) { char* r = p; p += (bytes + 255) & ~(size_t)255; return r; };
    int*   blockCntT  = (int*)alloc((size_t)nb * CSR_NBLK * 4);
    int*   tot        = (int*)alloc((size_t)nb * 4);
    int*   bucketBase = (int*)alloc((size_t)(nb + 1) * 4);
    int*   rowptr     = (int*)alloc((size_t)(n + 1) * 4);
    int*   csr        = (int*)alloc((size_t)E * 4);
    uint*  h1q        = (uint*)alloc((size_t)n * 32 * 4);    // fp8 x4 per uint
    float* as1        = (float*)alloc((size_t)n * 16);
    float* ad1        = (float*)alloc((size_t)n * 16);
    float* hrelu      = (float*)alloc((size_t)n * 128 * 4);
    uint*  h2q        = (uint*)alloc((size_t)n * 16 * 4);    // bf16 x2 per uint
    float* as2        = (float*)alloc((size_t)n * 8);
    float* ad2        = (float*)alloc((size_t)n * 8);
    float* hf         = (float*)alloc((size_t)n * 16 * 4);
    float* sums       = (float*)alloc((size_t)G * 16 * 4 + (size_t)G * 4);
    float* counts     = sums + G * 16;

    // edge staging buffer aliases hrelu; consumed by local_csr before agg1 writes.
    uint* ebuf = (uint*)hrelu;

    hipMemsetAsync(sums, 0, (size_t)G * 16 * 4 + (size_t)G * 4, stream);

    bucket_count_kernel<<<CSR_NBLK, 256, 0, stream>>>(dstA, E, chunk, nb, blockCntT);
    row_scan_kernel<<<nb, 512, 0, stream>>>(blockCntT, tot);
    total_scan_kernel<<<1, 1024, 0, stream>>>(tot, nb, bucketBase);
    bucket_scatter_kernel<<<CSR_NBLK, 256, 0, stream>>>(srcA, dstA, E, chunk, nb,
                                                        blockCntT, bucketBase, ebuf);
    local_csr_kernel<<<nb, 256, 0, stream>>>(ebuf, bucketBase, n, E, rowptr, csr);

    int gb = (n + 127) / 128;
    gemm_alpha_kernel<128, 4><<<gb, 256, 0, stream>>>(x, W1, a_src1, a_dst1, h1q, as1, ad1, n);
    agg1_kernel<<<(n + 3) / 4, 256, 0, stream>>>(as1, ad1, h1q, rowptr, csr, b1, hrelu, n);
    gemm_alpha_kernel<32, 2><<<gb, 256, 0, stream>>>(hrelu, W2, a_src2, a_dst2, h2q, as2, ad2, n);
    agg2_kernel<<<(n + 3) / 4, 256, 0, stream>>>(as2, ad2, h2q, rowptr, csr, b2, hf, n);
    pool_kernel<<<(n + 255) / 256, 256, 0, stream>>>(hf, batch, sums, counts, n);
    final_kernel<<<1, 64, 0, stream>>>(sums, counts, fcW, fcb, out, G);
}